// Round 12
// baseline (3907.968 us; speedup 1.0000x reference)
//
#include <hip/hip_runtime.h>
#include <hip/hip_fp16.h>
#include <cstdint>
#include <cstddef>

#define EPSF 2.220446049250313e-16f

// Sizes (fixed by the problem)
#define Bn   64
#define TP2n 1024
#define Tn   1023
#define Hn   256
#define H7n  1792
#define Kn   128
#define NEn  131

typedef _Float16 f16x2 __attribute__((ext_vector_type(2)));
typedef unsigned uintx4 __attribute__((ext_vector_type(4)));

__device__ __forceinline__ f16x2 u2h(unsigned u) { return __builtin_bit_cast(f16x2, u); }
__device__ __forceinline__ f16x2 f2h(float f)    { return __builtin_bit_cast(f16x2, f); }

__device__ __forceinline__ float fdot2f(f16x2 a, f16x2 b, float c) {
#if __has_builtin(__builtin_amdgcn_fdot2)
  return __builtin_amdgcn_fdot2(a, b, c, false);
#else
  return c + (float)a[0] * (float)b[0] + (float)a[1] * (float)b[1];
#endif
}

__device__ __forceinline__ float sigmf(float x) { return 1.f / (1.f + __expf(-x)); }

__device__ __forceinline__ float tanhfast(float x) {
  float t = __expf(2.f * fabsf(x));        // inf-safe: t=inf -> r=1
  float r = 1.f - 2.f / (t + 1.f);
  return copysignf(r, x);
}

__device__ __forceinline__ float softplusf(float x) {
  return fmaxf(x, 0.f) + log1pf(__expf(-fabsf(x)));
}

// fp8-e4m3 pair decode: u32 packed as bytes (b0,b2,b1,b3) -> two f16x2
// (e4m3->f16 exact modulo x2^8, folded into the per-row scale).
__device__ __forceinline__ void dec_dot2(unsigned x, float hp0, float hp1,
                                         float& accA, float& accB) {
  unsigned f0 = ((x & 0x007f007fu) << 7) | ((x & 0x00800080u) << 8);
  unsigned f1 = ((x & 0x7f007f00u) >> 1) | (x & 0x80008000u);
  accA = fdot2f(u2h(f0), f2h(hp0), accA);
  accB = fdot2f(u2h(f1), f2h(hp1), accB);
}

// Row permutation: r' = role*448 + g*64 + u  <->  orig r = g*256 + 64*role + u.
// Role r' block then owns ALL 7 gates of units [64*role, 64*role+64):
// Phase B is block-local; only h (512B) crosses blocks.
__device__ __host__ __forceinline__ int orig_row(int rp) {
  int role = rp / 448, i = rp % 448;
  return (i >> 6) * 256 + 64 * role + (i & 63);
}

// ---------------------------------------------------------------------------
// EWp[e][r'] = b[orig(r')] + sum_k Emb[e][k] * W[orig(r')][k]   (k<256)
__global__ void k_ew(const float* __restrict__ Emb, const float* __restrict__ W,
                     const float* __restrict__ bvec, float* __restrict__ EW) {
  int e = blockIdx.x;  // 0..130
  __shared__ float es[Hn];
  for (int k = threadIdx.x; k < Hn; k += blockDim.x) es[k] = Emb[e * Hn + k];
  __syncthreads();
  for (int rp = threadIdx.x; rp < H7n; rp += blockDim.x) {
    int r = orig_row(rp);
    const float* wr = W + (size_t)r * (2 * Hn);
    float acc = bvec[r];
#pragma unroll 4
    for (int k = 0; k < Hn; ++k) acc += es[k] * wr[k];
    EW[e * H7n + rp] = acc;
  }
}

// ---------------------------------------------------------------------------
// Quantize recurrent weights to fp8-e4m3 with per-row scale, PERMUTED rows.
// Word j of row r' = bytes (q[4j],q[4j+2],q[4j+1],q[4j+3]); sc[r'] = s*256.
__global__ __launch_bounds__(64) void k_wq(const float* __restrict__ W,
                                           unsigned* __restrict__ wq,
                                           float* __restrict__ sc) {
  const int rp = blockIdx.x;          // 0..1791 (permuted index)
  const int r  = orig_row(rp);
  const int j  = threadIdx.x;         // 0..63
  const float* wr = W + (size_t)r * 512 + 256;
  float4 wv = *reinterpret_cast<const float4*>(wr + 4 * j);
  float m = fmaxf(fmaxf(fabsf(wv.x), fabsf(wv.y)),
                  fmaxf(fabsf(wv.z), fabsf(wv.w)));
#pragma unroll
  for (int off = 32; off; off >>= 1) m = fmaxf(m, __shfl_xor(m, off));
  float inv_s = (m > 0.f) ? 448.f / m : 0.f;
  float v[4] = {wv.x, wv.y, wv.z, wv.w};
  unsigned b[4];
#pragma unroll
  for (int q = 0; q < 4; ++q) {
    float ay = fabsf(v[q]) * inv_s;     // in [0, 448]
    unsigned byte;
    if (ay < 0.015625f) {               // < 2^-6: denorm m*2^-9 (RNE)
      byte = (unsigned)(int)rintf(ay * 512.f);
    } else {                            // normal: rebias to 7, RNE 3-bit mant
      unsigned ub = __builtin_bit_cast(unsigned, ay);
      unsigned E  = (ub >> 23) & 255u;
      unsigned vv = ((E - 120u) << 23) | (ub & 0x7fffffu);
      byte = (vv + 0x7ffffu + ((vv >> 20) & 1u)) >> 20;
      if (byte > 0x7eu) byte = 0x7eu;
    }
    if (v[q] < 0.f) byte |= 0x80u;
    b[q] = byte;
  }
  wq[(size_t)rp * 64 + j] = b[0] | (b[2] << 8) | (b[1] << 16) | (b[3] << 24);
  if (j == 0) sc[rp] = (m / 448.f) * 256.f;
}

// ---------------------------------------------------------------------------
// Init accumulators and the h-exchange buffer. hx dwords get lsb=1 in both
// halves: first expected tag is 0, so poison / stale replay data can never
// false-positive the tag poll.
__global__ void k_init(float* __restrict__ acc, unsigned* __restrict__ hx) {
  int i = threadIdx.x;  // 1024 threads
  if (i < 192) acc[i] = 0.f;  // lam_acc[64], mask_acc[64], loglik_sum[64]
  for (int k = i; k < Bn * 256; k += 1024) hx[k] = 0x00010001u;
}

// ---------------------------------------------------------------------------
// Sequential CT-LSTM scan: 32 quads x 4 roles = 128 blocks; each quad runs
// TWO batches PHASE-SHIFTED (not lockstep — round-10's mistake). Round-11
// measured ~1us/step of naked MALL publish->poll latency. Here each batch's
// round-11 exchange protocol is kept verbatim, but batch A's poll is covered
// by batch B's compute and vice versa:
//   pollA -> PhaseA_A -> PhaseB_A+publishA -> pollB -> PhaseA_B ->
//   PhaseB_B+publishB -> (wrap)
// Cover per poll ~= one batch's PhaseA+PhaseB (~0.65us) > MALL RT, so polls
// hit their tag first-try. Also halves per-XCD L2 weight pressure (16
// blocks/XCD; each weight stream serves 2 batch-steps).
__global__ __launch_bounds__(448) void k_scan(
    const int* __restrict__ event, const float* __restrict__ dtime,
    const float* __restrict__ EW, const unsigned* __restrict__ wq,
    const float* __restrict__ sc, unsigned* __restrict__ hx,
    uint2* __restrict__ state) {
  const int x = blockIdx.x;            // 0..127
  // quad members share xcd (assumed xcd = blockIdx % 8); correctness does
  // not depend on the mapping.
  const int xcd = x & 7;
  const int role = (x >> 3) & 3;
  const int p = x >> 5;                // 0..3
  const int pair = xcd * 4 + p;        // 0..31
  const int bA = 2 * pair, bB = bA + 1;
  const int tid = threadIdx.x;
  const int row = role * 448 + tid;    // permuted row index

  __shared__ float    zbufA[448], zbufB[448];
  __shared__ unsigned hdsA[128], hdsB[128];  // h fp16-pairs, unit-major
  __shared__ int      ev_s[2][TP2n];
  __shared__ float    dt_s[2][TP2n];

  const uintx4* wp = reinterpret_cast<const uintx4*>(wq) + (size_t)row * 16;
  const float  sc_r = sc[row];
  unsigned* hxA = hx + (size_t)bA * 256;   // [par][128] dwords
  unsigned* hxB = hx + (size_t)bB * 256;

  for (int i = tid; i < TP2n; i += 448) {
    ev_s[0][i] = event[bA * TP2n + i];
    dt_s[0][i] = dtime[bA * TP2n + i];
    ev_s[1][i] = event[bB * TP2n + i];
    dt_s[1][i] = dtime[bB * TP2n + i];
  }
  if (tid < 128) { hdsA[tid] = 0u; hdsB[tid] = 0u; }
  __syncthreads();

  float cA = 0.f, cbA = 0.f, cB = 0.f, cbB = 0.f;  // unit state (tid<64)
  const int j_u = 64 * role + tid;                 // this thread's unit
  float ewA_pf = EW[(size_t)ev_s[0][0] * H7n + row];
  float ewB_pf = EW[(size_t)ev_s[1][0] * H7n + row];

  for (int t = 0; t < Tn; ++t) {
    const unsigned parP = (unsigned)((t - 1) & 1);        // poll slot (h(t))
    const unsigned tauP = (unsigned)(((t - 1) >> 1) & 1);
    const unsigned parQ = (unsigned)(t & 1);              // publish slot
    const unsigned tagQ = (unsigned)((t >> 1) & 1) * 0x00010001u;

    // ---- poll A: merge remote h_A(t) (published last iteration) ----
    if (t > 0 && tid >= 64 && tid < 160) {
      int k  = tid - 64;
      int rr = (role + 1 + (k >> 5)) & 3;
      int m  = 32 * rr + (k & 31);
      unsigned v;
      do {
        v = __hip_atomic_load(hxA + parP * 128 + m, __ATOMIC_RELAXED,
                              __HIP_MEMORY_SCOPE_AGENT);
      } while ((v & 1u) != tauP);
      hdsA[m] = v;                       // lsb-tag noise 2^-11, ok
    }
    __syncthreads();

    // ---- Phase A, batch A ----
    {
      float ewc = ewA_pf;
      ewA_pf = EW[(size_t)ev_s[0][t + 1] * H7n + row];
      float a0 = 0.f, a1 = 0.f, a2 = 0.f, a3 = 0.f;
      const float4* h4 = reinterpret_cast<const float4*>(hdsA);
#pragma unroll
      for (int i = 0; i < 16; ++i) {
        uintx4 ww = wp[i];
        float4 hA_ = h4[2 * i], hB_ = h4[2 * i + 1];
        dec_dot2(ww[0], hA_.x, hA_.y, a0, a1);
        dec_dot2(ww[1], hA_.z, hA_.w, a2, a3);
        dec_dot2(ww[2], hB_.x, hB_.y, a0, a1);
        dec_dot2(ww[3], hB_.z, hB_.w, a2, a3);
      }
      zbufA[tid] = ewc + sc_r * ((a0 + a1) + (a2 + a3));
    }
    __syncthreads();

    // ---- Phase B, batch A (tid<64) ----
    if (tid < 64) {
      float gi  = sigmf(zbufA[tid]);
      float gf  = sigmf(zbufA[64 + tid]);
      float go  = sigmf(zbufA[128 + tid]);
      float zc  = tanhfast(zbufA[192 + tid]);
      float gib = sigmf(zbufA[256 + tid]);
      float gfb = sigmf(zbufA[320 + tid]);
      float gd  = softplusf(zbufA[384 + tid]);
      float dt  = dt_s[0][t + 1];
      float ci  = gf * cA + gi * zc;
      float cbi = gfb * cbA + gib * zc;
      float cn  = cbi + (ci - cbi) * __expf(-gd * dt);
      float hn  = go * tanhfast(cn);
      cA = cn; cbA = cbi;
      reinterpret_cast<__half*>(hdsA)[j_u] = __float2half(hn);
      f16x2 p0; p0[0] = (_Float16)ci; p0[1] = (_Float16)cbi;
      f16x2 p1; p1[0] = (_Float16)gd; p1[1] = (_Float16)go;
      uint2 o;
      o.x = __builtin_bit_cast(unsigned, p0);
      o.y = __builtin_bit_cast(unsigned, p1);
      state[((size_t)bA * Tn + t) * Hn + j_u] = o;
    }
    __syncthreads();

    // ---- publish A (h_A(t+1)) + poll B (h_B(t)) concurrently ----
    if (t < Tn - 1 && tid < 32) {
      unsigned d = hdsA[32 * role + tid];
      __hip_atomic_store(hxA + parQ * 128 + 32 * role + tid,
                         (d & 0xFFFEFFFEu) | tagQ,
                         __ATOMIC_RELAXED, __HIP_MEMORY_SCOPE_AGENT);
    }
    if (t > 0 && tid >= 64 && tid < 160) {
      int k  = tid - 64;
      int rr = (role + 1 + (k >> 5)) & 3;
      int m  = 32 * rr + (k & 31);
      unsigned v;
      do {
        v = __hip_atomic_load(hxB + parP * 128 + m, __ATOMIC_RELAXED,
                              __HIP_MEMORY_SCOPE_AGENT);
      } while ((v & 1u) != tauP);
      hdsB[m] = v;
    }
    __syncthreads();

    // ---- Phase A, batch B ----
    {
      float ewc = ewB_pf;
      ewB_pf = EW[(size_t)ev_s[1][t + 1] * H7n + row];
      float a0 = 0.f, a1 = 0.f, a2 = 0.f, a3 = 0.f;
      const float4* h4 = reinterpret_cast<const float4*>(hdsB);
#pragma unroll
      for (int i = 0; i < 16; ++i) {
        uintx4 ww = wp[i];
        float4 hA_ = h4[2 * i], hB_ = h4[2 * i + 1];
        dec_dot2(ww[0], hA_.x, hA_.y, a0, a1);
        dec_dot2(ww[1], hA_.z, hA_.w, a2, a3);
        dec_dot2(ww[2], hB_.x, hB_.y, a0, a1);
        dec_dot2(ww[3], hB_.z, hB_.w, a2, a3);
      }
      zbufB[tid] = ewc + sc_r * ((a0 + a1) + (a2 + a3));
    }
    __syncthreads();

    // ---- Phase B, batch B (tid<64) ----
    if (tid < 64) {
      float gi  = sigmf(zbufB[tid]);
      float gf  = sigmf(zbufB[64 + tid]);
      float go  = sigmf(zbufB[128 + tid]);
      float zc  = tanhfast(zbufB[192 + tid]);
      float gib = sigmf(zbufB[256 + tid]);
      float gfb = sigmf(zbufB[320 + tid]);
      float gd  = softplusf(zbufB[384 + tid]);
      float dt  = dt_s[1][t + 1];
      float ci  = gf * cB + gi * zc;
      float cbi = gfb * cbB + gib * zc;
      float cn  = cbi + (ci - cbi) * __expf(-gd * dt);
      float hn  = go * tanhfast(cn);
      cB = cn; cbB = cbi;
      reinterpret_cast<__half*>(hdsB)[j_u] = __float2half(hn);
      f16x2 p0; p0[0] = (_Float16)ci; p0[1] = (_Float16)cbi;
      f16x2 p1; p1[0] = (_Float16)gd; p1[1] = (_Float16)go;
      uint2 o;
      o.x = __builtin_bit_cast(unsigned, p0);
      o.y = __builtin_bit_cast(unsigned, p1);
      state[((size_t)bB * Tn + t) * Hn + j_u] = o;
    }
    __syncthreads();

    // ---- publish B (h_B(t+1)); its poll happens next iteration, covered ----
    if (t < Tn - 1 && tid < 32) {
      unsigned d = hdsB[32 * role + tid];
      __hip_atomic_store(hxB + parQ * 128 + 32 * role + tid,
                         (d & 0xFFFEFFFEu) | tagQ,
                         __ATOMIC_RELAXED, __HIP_MEMORY_SCOPE_AGENT);
    }
    // no barrier needed: next iteration's pollA touches only hdsA-remote
    // dwords and global hxA; first consumer of hdsB is after the next bar.
  }
}

// ---------------------------------------------------------------------------
// log_lam_tgt, fully parallel: one wave per (b,t). Recomputes h_next from the
// packed state (same formula as sampling with dt = dtime[t+1]).
__global__ __launch_bounds__(256) void k_post(
    const uint2* __restrict__ state, const int* __restrict__ event,
    const float* __restrict__ dtime, const float* __restrict__ Wl,
    float* __restrict__ loglik_sum) {
  const int wid = blockIdx.x * 4 + (threadIdx.x >> 6);  // 0..65471
  const int lane = threadIdx.x & 63;
  const int b = wid / Tn;
  const int t = wid - b * Tn;
  const int tgt = event[b * TP2n + t + 1];
  if (tgt >= Kn) return;                                 // wave-uniform
  const float dtv = dtime[b * TP2n + t + 1];
  const uint2* srow = state + (size_t)wid * Hn;
  uint4 sA = *reinterpret_cast<const uint4*>(srow + lane * 4);
  uint4 sB = *reinterpret_cast<const uint4*>(srow + lane * 4 + 2);
  float4 wl = *reinterpret_cast<const float4*>(Wl + tgt * Hn + lane * 4);
  float h[4];
#pragma unroll
  for (int qq = 0; qq < 4; ++qq) {
    unsigned lo = (qq == 0) ? sA.x : (qq == 1) ? sA.z : (qq == 2) ? sB.x : sB.z;
    unsigned hi = (qq == 0) ? sA.y : (qq == 1) ? sA.w : (qq == 2) ? sB.y : sB.w;
    f16x2 p0 = u2h(lo), p1 = u2h(hi);
    float c = p0[0], cb = p0[1], gd = p1[0], go = p1[1];
    float cs = cb + (c - cb) * __expf(-gd * dtv);
    h[qq] = go * tanhfast(cs);
  }
  float d = h[0] * wl.x + h[1] * wl.y + h[2] * wl.z + h[3] * wl.w;
#pragma unroll
  for (int off = 32; off; off >>= 1) d += __shfl_down(d, off);
  if (lane == 0) atomicAdd(&loglik_sum[b], __logf(softplusf(d) + EPSF));
}

// ---------------------------------------------------------------------------
// Sampling: 1024 blocks (16/batch, 64 samples each) x 128 threads; thread k
// holds Wl row k in registers. Packed-state gather (one uint4/thread),
// next-sample prefetch.
__global__ __launch_bounds__(128) void k_samp(
    const uint2* __restrict__ state, const float* __restrict__ Wl,
    const int* __restrict__ sidx, const float* __restrict__ sdt,
    const float* __restrict__ smask,
    float* __restrict__ lam_acc, float* __restrict__ mask_acc) {
  const int blk = blockIdx.x;
  const int b = blk >> 4;
  const int base = (b << 10) + (blk & 15) * 64;
  const int tid = threadIdx.x;

  f16x2 wr[128];
  {
    const float* wrow = Wl + tid * Hn;
#pragma unroll
    for (int i = 0; i < 128; ++i) {
      f16x2 v; v[0] = (_Float16)wrow[2 * i]; v[1] = (_Float16)wrow[2 * i + 1];
      wr[i] = v;
    }
  }
  __shared__ float4 hy4[Hn / 8];
  __shared__ float  red[2];
  float accl = 0.f, accm = 0.f;

  int   row = sidx[base];
  float dtv = sdt[base];
  float mk  = smask[base];
  uint4 st = *reinterpret_cast<const uint4*>(state + (size_t)row * Hn + 2 * tid);

  for (int s = 0; s < 64; ++s) {
    f16x2 p0 = u2h(st.x), p1 = u2h(st.y);
    f16x2 q0 = u2h(st.z), q1 = u2h(st.w);
    float cs0 = (float)p0[1] + ((float)p0[0] - (float)p0[1]) * __expf(-(float)p1[0] * dtv);
    float cs1 = (float)q0[1] + ((float)q0[0] - (float)q0[1]) * __expf(-(float)q1[0] * dtv);
    f16x2 hp;
    hp[0] = (_Float16)((float)p1[1] * tanhfast(cs0));
    hp[1] = (_Float16)((float)q1[1] * tanhfast(cs1));
    reinterpret_cast<unsigned*>(hy4)[tid] = __builtin_bit_cast(unsigned, hp);

    uint4 st_n = st; float dt_n = dtv, mk_n = mk;
    if (s < 63) {
      int sg = base + s + 1;
      int r2 = sidx[sg];
      dt_n = sdt[sg];
      mk_n = smask[sg];
      st_n = *reinterpret_cast<const uint4*>(state + (size_t)r2 * Hn + 2 * tid);
    }
    __syncthreads();

    float d = 0.f;
#pragma unroll
    for (int q = 0; q < 32; ++q) {
      float4 hq = hy4[q];
      d = fdot2f(wr[4 * q + 0], f2h(hq.x), d);
      d = fdot2f(wr[4 * q + 1], f2h(hq.y), d);
      d = fdot2f(wr[4 * q + 2], f2h(hq.z), d);
      d = fdot2f(wr[4 * q + 3], f2h(hq.w), d);
    }
    float lam = softplusf(d);
#pragma unroll
    for (int off = 32; off; off >>= 1) lam += __shfl_down(lam, off);
    if ((tid & 63) == 0) red[tid >> 6] = lam;
    __syncthreads();
    if (tid == 0) {
      accl += (red[0] + red[1]) * mk;
      accm += mk;
    }
    st = st_n; dtv = dt_n; mk = mk_n;
  }
  if (tid == 0) {
    atomicAdd(&lam_acc[b], accl);
    atomicAdd(&mask_acc[b], accm);
  }
}

// ---------------------------------------------------------------------------
__global__ void k_final(const float* __restrict__ loglik_sum,
                        const float* __restrict__ lam_acc,
                        const float* __restrict__ mask_acc,
                        const float* __restrict__ duration,
                        float* __restrict__ out) {
  int b = threadIdx.x;
  if (b < Bn) out[b] = loglik_sum[b] - (lam_acc[b] / mask_acc[b]) * duration[b];
}

// ---------------------------------------------------------------------------
extern "C" void kernel_launch(void* const* d_in, const int* in_sizes, int n_in,
                              void* d_out, int out_size, void* d_ws, size_t ws_size,
                              hipStream_t stream) {
  const int*   event    = (const int*)d_in[0];
  const float* dtime    = (const float*)d_in[1];
  const float* duration = (const float*)d_in[3];
  const float* sdt      = (const float*)d_in[4];
  const int*   sidx     = (const int*)d_in[5];
  const float* smask    = (const float*)d_in[6];
  const float* Emb      = (const float*)d_in[7];
  const float* W        = (const float*)d_in[8];
  const float* bv       = (const float*)d_in[9];
  const float* Wl       = (const float*)d_in[10];

  char* ws = (char*)d_ws;
  // layout: EWp(0.94MB)@0 | wq(448KB)@1MB | acc(768B)@2MB | hx(64KB)@2MB+8KB |
  //         sc(7KB)@2MB+80KB | packed state(134MB)@4MB
  float*    EW         = (float*)(ws + 0);
  unsigned* wq         = (unsigned*)(ws + (1u << 20));
  float*    lam_acc    = (float*)(ws + (2u << 20));
  float*    mask_acc   = lam_acc + 64;
  float*    loglik_sum = lam_acc + 128;
  unsigned* hx         = (unsigned*)(ws + (2u << 20) + 8192);
  float*    sc         = (float*)(ws + (2u << 20) + 81920);
  uint2*    state      = (uint2*)(ws + (4u << 20));

  k_ew<<<dim3(NEn), dim3(256), 0, stream>>>(Emb, W, bv, EW);
  k_wq<<<dim3(H7n), dim3(64), 0, stream>>>(W, wq, sc);
  k_init<<<dim3(1), dim3(1024), 0, stream>>>(lam_acc, hx);
  k_scan<<<dim3(128), dim3(448), 0, stream>>>(event, dtime, EW, wq, sc, hx,
                                              state);
  k_post<<<dim3(16368), dim3(256), 0, stream>>>(state, event, dtime, Wl,
                                                loglik_sum);
  k_samp<<<dim3(1024), dim3(128), 0, stream>>>(state, Wl, sidx, sdt, smask,
                                               lam_acc, mask_acc);
  k_final<<<dim3(1), dim3(64), 0, stream>>>(loglik_sum, lam_acc, mask_acc,
                                            duration, (float*)d_out);
}

// Round 13
// 2730.930 us; speedup vs baseline: 1.4310x; 1.4310x over previous
//
#include <hip/hip_runtime.h>
#include <hip/hip_fp16.h>
#include <cstdint>
#include <cstddef>

#define EPSF 2.220446049250313e-16f

// Sizes (fixed by the problem)
#define Bn   64
#define TP2n 1024
#define Tn   1023
#define Hn   256
#define H7n  1792
#define Kn   128
#define NEn  131

typedef _Float16 f16x2 __attribute__((ext_vector_type(2)));
typedef unsigned uintx4 __attribute__((ext_vector_type(4)));

__device__ __forceinline__ f16x2 u2h(unsigned u) { return __builtin_bit_cast(f16x2, u); }
__device__ __forceinline__ f16x2 f2h(float f)    { return __builtin_bit_cast(f16x2, f); }

__device__ __forceinline__ float fdot2f(f16x2 a, f16x2 b, float c) {
#if __has_builtin(__builtin_amdgcn_fdot2)
  return __builtin_amdgcn_fdot2(a, b, c, false);
#else
  return c + (float)a[0] * (float)b[0] + (float)a[1] * (float)b[1];
#endif
}

__device__ __forceinline__ float sigmf(float x) { return 1.f / (1.f + __expf(-x)); }

__device__ __forceinline__ float tanhfast(float x) {
  float t = __expf(2.f * fabsf(x));        // inf-safe: t=inf -> r=1
  float r = 1.f - 2.f / (t + 1.f);
  return copysignf(r, x);
}

__device__ __forceinline__ float softplusf(float x) {
  return fmaxf(x, 0.f) + log1pf(__expf(-fabsf(x)));
}

// fp8-e4m3 pair decode: u32 packed as bytes (b0,b2,b1,b3) -> two f16x2
// (e4m3->f16 exact modulo x2^8, folded into the per-row scale).
__device__ __forceinline__ void dec_dot2(unsigned x, float hp0, float hp1,
                                         float& accA, float& accB) {
  unsigned f0 = ((x & 0x007f007fu) << 7) | ((x & 0x00800080u) << 8);
  unsigned f1 = ((x & 0x7f007f00u) >> 1) | (x & 0x80008000u);
  accA = fdot2f(u2h(f0), f2h(hp0), accA);
  accB = fdot2f(u2h(f1), f2h(hp1), accB);
}

// Row permutation: r' = role*448 + g*64 + u  <->  orig r = g*256 + 64*role + u.
// Role r' block then owns ALL 7 gates of units [64*role, 64*role+64):
// Phase B is block-local; only h (512B) crosses blocks.
__device__ __host__ __forceinline__ int orig_row(int rp) {
  int role = rp / 448, i = rp % 448;
  return (i >> 6) * 256 + 64 * role + (i & 63);
}

// ---------------------------------------------------------------------------
// EWp[e][r'] = b[orig(r')] + sum_k Emb[e][k] * W[orig(r')][k]   (k<256)
__global__ void k_ew(const float* __restrict__ Emb, const float* __restrict__ W,
                     const float* __restrict__ bvec, float* __restrict__ EW) {
  int e = blockIdx.x;  // 0..130
  __shared__ float es[Hn];
  for (int k = threadIdx.x; k < Hn; k += blockDim.x) es[k] = Emb[e * Hn + k];
  __syncthreads();
  for (int rp = threadIdx.x; rp < H7n; rp += blockDim.x) {
    int r = orig_row(rp);
    const float* wr = W + (size_t)r * (2 * Hn);
    float acc = bvec[r];
#pragma unroll 4
    for (int k = 0; k < Hn; ++k) acc += es[k] * wr[k];
    EW[e * H7n + rp] = acc;
  }
}

// ---------------------------------------------------------------------------
// Quantize recurrent weights to fp8-e4m3 with per-row scale, PERMUTED rows.
// Word j of row r' = bytes (q[4j],q[4j+2],q[4j+1],q[4j+3]); sc[r'] = s*256.
__global__ __launch_bounds__(64) void k_wq(const float* __restrict__ W,
                                           unsigned* __restrict__ wq,
                                           float* __restrict__ sc) {
  const int rp = blockIdx.x;          // 0..1791 (permuted index)
  const int r  = orig_row(rp);
  const int j  = threadIdx.x;         // 0..63
  const float* wr = W + (size_t)r * 512 + 256;
  float4 wv = *reinterpret_cast<const float4*>(wr + 4 * j);
  float m = fmaxf(fmaxf(fabsf(wv.x), fabsf(wv.y)),
                  fmaxf(fabsf(wv.z), fabsf(wv.w)));
#pragma unroll
  for (int off = 32; off; off >>= 1) m = fmaxf(m, __shfl_xor(m, off));
  float inv_s = (m > 0.f) ? 448.f / m : 0.f;
  float v[4] = {wv.x, wv.y, wv.z, wv.w};
  unsigned b[4];
#pragma unroll
  for (int q = 0; q < 4; ++q) {
    float ay = fabsf(v[q]) * inv_s;     // in [0, 448]
    unsigned byte;
    if (ay < 0.015625f) {               // < 2^-6: denorm m*2^-9 (RNE)
      byte = (unsigned)(int)rintf(ay * 512.f);
    } else {                            // normal: rebias to 7, RNE 3-bit mant
      unsigned ub = __builtin_bit_cast(unsigned, ay);
      unsigned E  = (ub >> 23) & 255u;
      unsigned vv = ((E - 120u) << 23) | (ub & 0x7fffffu);
      byte = (vv + 0x7ffffu + ((vv >> 20) & 1u)) >> 20;
      if (byte > 0x7eu) byte = 0x7eu;
    }
    if (v[q] < 0.f) byte |= 0x80u;
    b[q] = byte;
  }
  wq[(size_t)rp * 64 + j] = b[0] | (b[2] << 8) | (b[1] << 16) | (b[3] << 24);
  if (j == 0) sc[rp] = (m / 448.f) * 256.f;
}

// ---------------------------------------------------------------------------
// Init accumulators and the h-exchange buffer. hx dwords get lsb=1 in both
// halves: first expected tag is 0, so poison / stale replay data can never
// false-positive the tag poll.
__global__ void k_init(float* __restrict__ acc, unsigned* __restrict__ hx) {
  int i = threadIdx.x;  // 1024 threads
  if (i < 192) acc[i] = 0.f;  // lam_acc[64], mask_acc[64], loglik_sum[64]
  for (int k = i; k < Bn * 256; k += 1024) hx[k] = 0x00010001u;
}

// ---------------------------------------------------------------------------
// Sequential CT-LSTM scan, 4 blocks/batch, 448 threads, 1 permuted row each
// (round-11 structure, proven 2.0us/step). Round-12 lesson: never serialize
// independent batches into the t-loop; hide latency WITHIN the step. This
// round the exchange phase is folded into Phase B:
//  - wave 0 (tid<64) computes h(t+1) and PUBLISHES the 32 tagged dwords
//    directly via wave-internal shuffles (units 2k,2k+1 are adjacent lanes)
//    — publish needs no barrier;
//  - waves 1-2 (tid 64..159) POLL the 3 remote blocks' h(t+1) concurrently,
//    covered by wave 0's gate math; they write only remote hds slots.
// 2 barriers/step instead of 3; the MALL round trip is (partly) covered.
// par/tag arithmetic identical to round 11 (publish & poll at step t both
// use par=t&1, tau=(t>>1)&1); reuse-distance-2 enforced by the recurrence.
__global__ __launch_bounds__(448) void k_scan(
    const int* __restrict__ event, const float* __restrict__ dtime,
    const float* __restrict__ EW, const unsigned* __restrict__ wq,
    const float* __restrict__ sc, unsigned* __restrict__ hx,
    uint2* __restrict__ state) {
  const int x = blockIdx.x;
  // co-locate a batch's 4 blocks on one XCD (assumed xcd = blockIdx % 8);
  // correctness does not depend on this mapping.
  const int xcd = x & 7, q = x >> 3;
  const int b = xcd * 8 + (q >> 2);
  const int role = q & 3;
  const int tid = threadIdx.x;
  const int row = role * 448 + tid;     // permuted row index

  __shared__ float    zbuf[448];        // this block's z slice (local!)
  __shared__ unsigned hds[128];         // h fp16-pairs, unit-major (256 halves)
  __shared__ int      ev_s[TP2n];
  __shared__ float    dt_s[TP2n];

  const uintx4* wp = reinterpret_cast<const uintx4*>(wq) + (size_t)row * 16;
  const float  sc_r = sc[row];
  unsigned* hxb = hx + (size_t)b * 256;   // [par][128] dwords

  for (int i = tid; i < TP2n; i += 448) {
    ev_s[i] = event[b * TP2n + i];
    dt_s[i] = dtime[b * TP2n + i];
  }
  if (tid < 128) hds[tid] = 0u;
  __syncthreads();

  float c_r = 0.f, cb_r = 0.f;          // unit state (threads 0..63)
  const int j_u = 64 * role + tid;      // this thread's unit (tid<64)
  float ew_pf = EW[(size_t)ev_s[0] * H7n + row];

  for (int t = 0; t < Tn; ++t) {
    float ewc = ew_pf;
    ew_pf = EW[(size_t)ev_s[t + 1] * H7n + row];  // next-step prefetch

    // ---- Phase A: z for this row (fp8 weights, h broadcast from LDS) ----
    float a0 = 0.f, a1 = 0.f, a2 = 0.f, a3 = 0.f;
    const float4* h4 = reinterpret_cast<const float4*>(hds);
#pragma unroll
    for (int i = 0; i < 16; ++i) {
      uintx4 ww = wp[i];               // 16 fp8 weights (cols 16i..16i+15)
      float4 hA = h4[2 * i];
      float4 hB = h4[2 * i + 1];
      dec_dot2(ww[0], hA.x, hA.y, a0, a1);
      dec_dot2(ww[1], hA.z, hA.w, a2, a3);
      dec_dot2(ww[2], hB.x, hB.y, a0, a1);
      dec_dot2(ww[3], hB.z, hB.w, a2, a3);
    }
    zbuf[tid] = ewc + sc_r * ((a0 + a1) + (a2 + a3));
    __syncthreads();

    const unsigned parQ = (unsigned)(t & 1);
    const unsigned tauQ = (unsigned)((t >> 1) & 1);
    const unsigned tagw = tauQ * 0x00010001u;

    // ---- Phase B (wave 0) + fused publish; concurrent remote poll ----
    if (tid < 64) {
      float gi  = sigmf(zbuf[tid]);
      float gf  = sigmf(zbuf[64 + tid]);
      float go  = sigmf(zbuf[128 + tid]);
      float zc  = tanhfast(zbuf[192 + tid]);
      float gib = sigmf(zbuf[256 + tid]);
      float gfb = sigmf(zbuf[320 + tid]);
      float gd  = softplusf(zbuf[384 + tid]);
      float dt  = dt_s[t + 1];
      float ci  = gf * c_r + gi * zc;
      float cbi = gfb * cb_r + gib * zc;
      float cn  = cbi + (ci - cbi) * __expf(-gd * dt);
      float hn  = go * tanhfast(cn);
      c_r = cn; cb_r = cbi;
      __half hh = __float2half(hn);
      unsigned hu = (unsigned)__half_as_ushort(hh);
      reinterpret_cast<__half*>(hds)[j_u] = hh;
      // publish own 32 tagged dwords via wave-internal pair shuffle
      unsigned u0 = __shfl(hu, 2 * tid);       // lane k: h of unit 2k
      unsigned u1 = __shfl(hu, 2 * tid + 1);   //          h of unit 2k+1
      if (t < Tn - 1 && tid < 32) {
        unsigned d = ((u0 & 0xFFFEu) | ((u1 & 0xFFFEu) << 16)) | tagw;
        __hip_atomic_store(hxb + parQ * 128 + 32 * role + tid, d,
                           __ATOMIC_RELAXED, __HIP_MEMORY_SCOPE_AGENT);
      }
      f16x2 p0; p0[0] = (_Float16)ci; p0[1] = (_Float16)cbi;
      f16x2 p1; p1[0] = (_Float16)gd; p1[1] = (_Float16)go;
      uint2 o;
      o.x = __builtin_bit_cast(unsigned, p0);
      o.y = __builtin_bit_cast(unsigned, p1);
      state[((size_t)b * Tn + t) * Hn + j_u] = o;
    } else if (tid < 160 && t < Tn - 1) {
      // waves 1-2: poll remote h(t+1); covered by wave 0's Phase B
      int k  = tid - 64;                       // 0..95
      int rr = (role + 1 + (k >> 5)) & 3;      // the 3 other roles
      int m  = 32 * rr + (k & 31);
      unsigned v;
      do {
        v = __hip_atomic_load(hxb + parQ * 128 + m, __ATOMIC_RELAXED,
                              __HIP_MEMORY_SCOPE_AGENT);
      } while ((v & 1u) != tauQ);
      hds[m] = v;                              // lsb-tag noise: 2^-11, ok
    }
    __syncthreads();
  }
}

// ---------------------------------------------------------------------------
// log_lam_tgt, fully parallel: one wave per (b,t). Recomputes h_next from the
// packed state (same formula as sampling with dt = dtime[t+1]).
__global__ __launch_bounds__(256) void k_post(
    const uint2* __restrict__ state, const int* __restrict__ event,
    const float* __restrict__ dtime, const float* __restrict__ Wl,
    float* __restrict__ loglik_sum) {
  const int wid = blockIdx.x * 4 + (threadIdx.x >> 6);  // 0..65471
  const int lane = threadIdx.x & 63;
  const int b = wid / Tn;
  const int t = wid - b * Tn;
  const int tgt = event[b * TP2n + t + 1];
  if (tgt >= Kn) return;                                 // wave-uniform
  const float dtv = dtime[b * TP2n + t + 1];
  const uint2* srow = state + (size_t)wid * Hn;
  uint4 sA = *reinterpret_cast<const uint4*>(srow + lane * 4);
  uint4 sB = *reinterpret_cast<const uint4*>(srow + lane * 4 + 2);
  float4 wl = *reinterpret_cast<const float4*>(Wl + tgt * Hn + lane * 4);
  float h[4];
#pragma unroll
  for (int qq = 0; qq < 4; ++qq) {
    unsigned lo = (qq == 0) ? sA.x : (qq == 1) ? sA.z : (qq == 2) ? sB.x : sB.z;
    unsigned hi = (qq == 0) ? sA.y : (qq == 1) ? sA.w : (qq == 2) ? sB.y : sB.w;
    f16x2 p0 = u2h(lo), p1 = u2h(hi);
    float c = p0[0], cb = p0[1], gd = p1[0], go = p1[1];
    float cs = cb + (c - cb) * __expf(-gd * dtv);
    h[qq] = go * tanhfast(cs);
  }
  float d = h[0] * wl.x + h[1] * wl.y + h[2] * wl.z + h[3] * wl.w;
#pragma unroll
  for (int off = 32; off; off >>= 1) d += __shfl_down(d, off);
  if (lane == 0) atomicAdd(&loglik_sum[b], __logf(softplusf(d) + EPSF));
}

// ---------------------------------------------------------------------------
// Sampling: 1024 blocks (16/batch, 64 samples each) x 128 threads; thread k
// holds Wl row k in registers. Packed-state gather (one uint4/thread),
// next-sample prefetch.
__global__ __launch_bounds__(128) void k_samp(
    const uint2* __restrict__ state, const float* __restrict__ Wl,
    const int* __restrict__ sidx, const float* __restrict__ sdt,
    const float* __restrict__ smask,
    float* __restrict__ lam_acc, float* __restrict__ mask_acc) {
  const int blk = blockIdx.x;
  const int b = blk >> 4;
  const int base = (b << 10) + (blk & 15) * 64;
  const int tid = threadIdx.x;

  f16x2 wr[128];
  {
    const float* wrow = Wl + tid * Hn;
#pragma unroll
    for (int i = 0; i < 128; ++i) {
      f16x2 v; v[0] = (_Float16)wrow[2 * i]; v[1] = (_Float16)wrow[2 * i + 1];
      wr[i] = v;
    }
  }
  __shared__ float4 hy4[Hn / 8];
  __shared__ float  red[2];
  float accl = 0.f, accm = 0.f;

  int   row = sidx[base];
  float dtv = sdt[base];
  float mk  = smask[base];
  uint4 st = *reinterpret_cast<const uint4*>(state + (size_t)row * Hn + 2 * tid);

  for (int s = 0; s < 64; ++s) {
    f16x2 p0 = u2h(st.x), p1 = u2h(st.y);
    f16x2 q0 = u2h(st.z), q1 = u2h(st.w);
    float cs0 = (float)p0[1] + ((float)p0[0] - (float)p0[1]) * __expf(-(float)p1[0] * dtv);
    float cs1 = (float)q0[1] + ((float)q0[0] - (float)q0[1]) * __expf(-(float)q1[0] * dtv);
    f16x2 hp;
    hp[0] = (_Float16)((float)p1[1] * tanhfast(cs0));
    hp[1] = (_Float16)((float)q1[1] * tanhfast(cs1));
    reinterpret_cast<unsigned*>(hy4)[tid] = __builtin_bit_cast(unsigned, hp);

    uint4 st_n = st; float dt_n = dtv, mk_n = mk;
    if (s < 63) {
      int sg = base + s + 1;
      int r2 = sidx[sg];
      dt_n = sdt[sg];
      mk_n = smask[sg];
      st_n = *reinterpret_cast<const uint4*>(state + (size_t)r2 * Hn + 2 * tid);
    }
    __syncthreads();

    float d = 0.f;
#pragma unroll
    for (int q = 0; q < 32; ++q) {
      float4 hq = hy4[q];
      d = fdot2f(wr[4 * q + 0], f2h(hq.x), d);
      d = fdot2f(wr[4 * q + 1], f2h(hq.y), d);
      d = fdot2f(wr[4 * q + 2], f2h(hq.z), d);
      d = fdot2f(wr[4 * q + 3], f2h(hq.w), d);
    }
    float lam = softplusf(d);
#pragma unroll
    for (int off = 32; off; off >>= 1) lam += __shfl_down(lam, off);
    if ((tid & 63) == 0) red[tid >> 6] = lam;
    __syncthreads();
    if (tid == 0) {
      accl += (red[0] + red[1]) * mk;
      accm += mk;
    }
    st = st_n; dtv = dt_n; mk = mk_n;
  }
  if (tid == 0) {
    atomicAdd(&lam_acc[b], accl);
    atomicAdd(&mask_acc[b], accm);
  }
}

// ---------------------------------------------------------------------------
__global__ void k_final(const float* __restrict__ loglik_sum,
                        const float* __restrict__ lam_acc,
                        const float* __restrict__ mask_acc,
                        const float* __restrict__ duration,
                        float* __restrict__ out) {
  int b = threadIdx.x;
  if (b < Bn) out[b] = loglik_sum[b] - (lam_acc[b] / mask_acc[b]) * duration[b];
}

// ---------------------------------------------------------------------------
extern "C" void kernel_launch(void* const* d_in, const int* in_sizes, int n_in,
                              void* d_out, int out_size, void* d_ws, size_t ws_size,
                              hipStream_t stream) {
  const int*   event    = (const int*)d_in[0];
  const float* dtime    = (const float*)d_in[1];
  const float* duration = (const float*)d_in[3];
  const float* sdt      = (const float*)d_in[4];
  const int*   sidx     = (const int*)d_in[5];
  const float* smask    = (const float*)d_in[6];
  const float* Emb      = (const float*)d_in[7];
  const float* W        = (const float*)d_in[8];
  const float* bv       = (const float*)d_in[9];
  const float* Wl       = (const float*)d_in[10];

  char* ws = (char*)d_ws;
  // layout: EWp(0.94MB)@0 | wq(448KB)@1MB | acc(768B)@2MB | hx(64KB)@2MB+8KB |
  //         sc(7KB)@2MB+80KB | packed state(134MB)@4MB
  float*    EW         = (float*)(ws + 0);
  unsigned* wq         = (unsigned*)(ws + (1u << 20));
  float*    lam_acc    = (float*)(ws + (2u << 20));
  float*    mask_acc   = lam_acc + 64;
  float*    loglik_sum = lam_acc + 128;
  unsigned* hx         = (unsigned*)(ws + (2u << 20) + 8192);
  float*    sc         = (float*)(ws + (2u << 20) + 81920);
  uint2*    state      = (uint2*)(ws + (4u << 20));

  k_ew<<<dim3(NEn), dim3(256), 0, stream>>>(Emb, W, bv, EW);
  k_wq<<<dim3(H7n), dim3(64), 0, stream>>>(W, wq, sc);
  k_init<<<dim3(1), dim3(1024), 0, stream>>>(lam_acc, hx);
  k_scan<<<dim3(256), dim3(448), 0, stream>>>(event, dtime, EW, wq, sc, hx,
                                              state);
  k_post<<<dim3(16368), dim3(256), 0, stream>>>(state, event, dtime, Wl,
                                                loglik_sum);
  k_samp<<<dim3(1024), dim3(128), 0, stream>>>(state, Wl, sidx, sdt, smask,
                                               lam_acc, mask_acc);
  k_final<<<dim3(1), dim3(64), 0, stream>>>(loglik_sum, lam_acc, mask_acc,
                                            duration, (float*)d_out);
}

// Round 14
// 2481.133 us; speedup vs baseline: 1.5751x; 1.1007x over previous
//
#include <hip/hip_runtime.h>
#include <hip/hip_fp16.h>
#include <cstdint>
#include <cstddef>

#define EPSF 2.220446049250313e-16f

// Sizes (fixed by the problem)
#define Bn   64
#define TP2n 1024
#define Tn   1023
#define Hn   256
#define H7n  1792
#define Kn   128
#define NEn  131

typedef _Float16 f16x2 __attribute__((ext_vector_type(2)));
typedef unsigned uintx4 __attribute__((ext_vector_type(4)));

__device__ __forceinline__ f16x2 u2h(unsigned u) { return __builtin_bit_cast(f16x2, u); }
__device__ __forceinline__ f16x2 f2h(float f)    { return __builtin_bit_cast(f16x2, f); }

__device__ __forceinline__ float fdot2f(f16x2 a, f16x2 b, float c) {
#if __has_builtin(__builtin_amdgcn_fdot2)
  return __builtin_amdgcn_fdot2(a, b, c, false);
#else
  return c + (float)a[0] * (float)b[0] + (float)a[1] * (float)b[1];
#endif
}

// 4-way signed-byte dot product with int32 accumulate (v_dot4_i32_i8).
__device__ __forceinline__ int sdot4f(unsigned a, unsigned b, int c) {
#if __has_builtin(__builtin_amdgcn_sdot4)
  return __builtin_amdgcn_sdot4((int)a, (int)b, c, false);
#else
  int r = c;
#pragma unroll
  for (int i = 0; i < 4; ++i) {
    int av = ((int)(a << (24 - 8 * i))) >> 24;
    int bv = ((int)(b << (24 - 8 * i))) >> 24;
    r += av * bv;
  }
  return r;
#endif
}

__device__ __forceinline__ float sigmf(float x) { return 1.f / (1.f + __expf(-x)); }

__device__ __forceinline__ float tanhfast(float x) {
  float t = __expf(2.f * fabsf(x));        // inf-safe: t=inf -> r=1
  float r = 1.f - 2.f / (t + 1.f);
  return copysignf(r, x);
}

__device__ __forceinline__ float softplusf(float x) {
  return fmaxf(x, 0.f) + log1pf(__expf(-fabsf(x)));
}

// Row permutation: r' = role*448 + g*64 + u  <->  orig r = g*256 + 64*role + u.
// Role r' block then owns ALL 7 gates of units [64*role, 64*role+64):
// Phase B is block-local; only h (256 int8) crosses blocks.
__device__ __host__ __forceinline__ int orig_row(int rp) {
  int role = rp / 448, i = rp % 448;
  return (i >> 6) * 256 + 64 * role + (i & 63);
}

// ---------------------------------------------------------------------------
// EWp[e][r'] = b[orig(r')] + sum_k Emb[e][k] * W[orig(r')][k]   (k<256)
__global__ void k_ew(const float* __restrict__ Emb, const float* __restrict__ W,
                     const float* __restrict__ bvec, float* __restrict__ EW) {
  int e = blockIdx.x;  // 0..130
  __shared__ float es[Hn];
  for (int k = threadIdx.x; k < Hn; k += blockDim.x) es[k] = Emb[e * Hn + k];
  __syncthreads();
  for (int rp = threadIdx.x; rp < H7n; rp += blockDim.x) {
    int r = orig_row(rp);
    const float* wr = W + (size_t)r * (2 * Hn);
    float acc = bvec[r];
#pragma unroll 4
    for (int k = 0; k < Hn; ++k) acc += es[k] * wr[k];
    EW[e * H7n + rp] = acc;
  }
}

// ---------------------------------------------------------------------------
// Quantize recurrent weights to int8 with per-row scale, PERMUTED rows.
// Dword j of row r' = bytes (k=4j..4j+3), natural order (matches sdot4 with
// h packed unit-major 4/dword). sc[r'] = max/127^2 (weight scale x h scale).
__global__ __launch_bounds__(64) void k_wq8(const float* __restrict__ W,
                                            unsigned* __restrict__ wq,
                                            float* __restrict__ sc) {
  const int rp = blockIdx.x;          // 0..1791 (permuted index)
  const int r  = orig_row(rp);
  const int j  = threadIdx.x;         // 0..63
  const float* wr = W + (size_t)r * 512 + 256;
  float4 wv = *reinterpret_cast<const float4*>(wr + 4 * j);
  float m = fmaxf(fmaxf(fabsf(wv.x), fabsf(wv.y)),
                  fmaxf(fabsf(wv.z), fabsf(wv.w)));
#pragma unroll
  for (int off = 32; off; off >>= 1) m = fmaxf(m, __shfl_xor(m, off));
  float inv = (m > 0.f) ? 127.f / m : 0.f;
  float v[4] = {wv.x, wv.y, wv.z, wv.w};
  unsigned d = 0;
#pragma unroll
  for (int q = 0; q < 4; ++q) {
    float s = fminf(fmaxf(v[q] * inv, -127.f), 127.f);
    unsigned byte = (unsigned)((int)rintf(s)) & 255u;
    d |= byte << (8 * q);
  }
  wq[(size_t)rp * 64 + j] = d;
  if (j == 0) sc[rp] = m / (127.f * 127.f);
}

// ---------------------------------------------------------------------------
// Init accumulators and the h-exchange buffer. hx dwords get lsb=1: first
// expected tag is 0, so poison / stale replay data can never false-positive.
__global__ void k_init(float* __restrict__ acc, unsigned* __restrict__ hx) {
  int i = threadIdx.x;  // 1024 threads
  if (i < 192) acc[i] = 0.f;  // lam_acc[64], mask_acc[64], loglik_sum[64]
  for (int k = i; k < Bn * 128; k += 1024) hx[k] = 1u;
}

// ---------------------------------------------------------------------------
// Sequential CT-LSTM scan, 4 blocks/batch, 448 threads, 1 permuted row each
// (round-11/13 structure, proven 2.0us/step; residual = weight ingest +
// Phase A VALU + 2 barriers). This round: int8 weights x int8 h via
// v_dot4_i32_i8 — zero decode VALU (fp8's mask-shift+dot2 was ~4.5 ops per
// 2 weights; sdot4 is 1 op per 4). h is quantized to int8 in Phase B
// (round(h*127), packed 4/dword by wave-0 shuffles), published as 16 tagged
// dwords/role (tag = dword lsb, par/tau protocol identical to r11), polled
// by 48 lanes of wave 1 concurrently with wave 0's gate math.
__global__ __launch_bounds__(448) void k_scan(
    const int* __restrict__ event, const float* __restrict__ dtime,
    const float* __restrict__ EW, const unsigned* __restrict__ wq,
    const float* __restrict__ sc, unsigned* __restrict__ hx,
    uint2* __restrict__ state) {
  const int x = blockIdx.x;
  // co-locate a batch's 4 blocks on one XCD (assumed xcd = blockIdx % 8);
  // correctness does not depend on this mapping.
  const int xcd = x & 7, q = x >> 3;
  const int b = xcd * 8 + (q >> 2);
  const int role = q & 3;
  const int tid = threadIdx.x;
  const int row = role * 448 + tid;     // permuted row index

  __shared__ float    zbuf[448];        // this block's z slice (local!)
  __shared__ unsigned hds8[64];         // 256 int8 h, unit-major 4/dword
  __shared__ int      ev_s[TP2n];
  __shared__ float    dt_s[TP2n];

  const uintx4* wp = reinterpret_cast<const uintx4*>(wq) + (size_t)row * 16;
  const float  sc_r = sc[row];
  unsigned* hxb = hx + (size_t)b * 128;   // [par][64] dwords

  for (int i = tid; i < TP2n; i += 448) {
    ev_s[i] = event[b * TP2n + i];
    dt_s[i] = dtime[b * TP2n + i];
  }
  if (tid < 64) hds8[tid] = 0u;
  __syncthreads();

  float c_r = 0.f, cb_r = 0.f;          // unit state (threads 0..63)
  const int j_u = 64 * role + tid;      // this thread's unit (tid<64)
  float ew_pf = EW[(size_t)ev_s[0] * H7n + row];

  for (int t = 0; t < Tn; ++t) {
    float ewc = ew_pf;
    ew_pf = EW[(size_t)ev_s[t + 1] * H7n + row];  // next-step prefetch

    // ---- Phase A: z for this row (int8 weights x int8 h, sdot4) ----
    int acc0 = 0, acc1 = 0, acc2 = 0, acc3 = 0;
    const uintx4* h8 = reinterpret_cast<const uintx4*>(hds8);
#pragma unroll
    for (int i = 0; i < 16; ++i) {
      uintx4 ww = wp[i];               // 16 int8 weights (cols 16i..16i+15)
      uintx4 hh = h8[i];               // uniform-address broadcast read
      acc0 = sdot4f(ww[0], hh[0], acc0);
      acc1 = sdot4f(ww[1], hh[1], acc1);
      acc2 = sdot4f(ww[2], hh[2], acc2);
      acc3 = sdot4f(ww[3], hh[3], acc3);
    }
    zbuf[tid] = ewc + sc_r * (float)((acc0 + acc1) + (acc2 + acc3));
    __syncthreads();

    const unsigned parQ = (unsigned)(t & 1);
    const unsigned tauQ = (unsigned)((t >> 1) & 1);

    // ---- Phase B (wave 0) + fused int8 pack/publish; concurrent poll ----
    if (tid < 64) {
      float gi  = sigmf(zbuf[tid]);
      float gf  = sigmf(zbuf[64 + tid]);
      float go  = sigmf(zbuf[128 + tid]);
      float zc  = tanhfast(zbuf[192 + tid]);
      float gib = sigmf(zbuf[256 + tid]);
      float gfb = sigmf(zbuf[320 + tid]);
      float gd  = softplusf(zbuf[384 + tid]);
      float dt  = dt_s[t + 1];
      float ci  = gf * c_r + gi * zc;
      float cbi = gfb * cb_r + gib * zc;
      float cn  = cbi + (ci - cbi) * __expf(-gd * dt);
      float hn  = go * tanhfast(cn);
      c_r = cn; cb_r = cbi;
      // int8 h, packed 4 units/dword via wave-internal shuffles
      unsigned bq = (unsigned)((int)rintf(
                        fminf(fmaxf(hn * 127.f, -127.f), 127.f))) & 255u;
      unsigned u0 = __shfl(bq, 4 * (tid & 15));
      unsigned u1 = __shfl(bq, 4 * (tid & 15) + 1);
      unsigned u2 = __shfl(bq, 4 * (tid & 15) + 2);
      unsigned u3 = __shfl(bq, 4 * (tid & 15) + 3);
      if (tid < 16) {
        unsigned d = u0 | (u1 << 8) | (u2 << 16) | (u3 << 24);
        hds8[16 * role + tid] = d;     // own copy: full precision
        if (t < Tn - 1)
          __hip_atomic_store(hxb + parQ * 64 + 16 * role + tid,
                             (d & 0xFFFFFFFEu) | tauQ,
                             __ATOMIC_RELAXED, __HIP_MEMORY_SCOPE_AGENT);
      }
      f16x2 p0; p0[0] = (_Float16)ci; p0[1] = (_Float16)cbi;
      f16x2 p1; p1[0] = (_Float16)gd; p1[1] = (_Float16)go;
      uint2 o;
      o.x = __builtin_bit_cast(unsigned, p0);
      o.y = __builtin_bit_cast(unsigned, p1);
      state[((size_t)b * Tn + t) * Hn + j_u] = o;
    } else if (tid < 112 && t < Tn - 1) {
      // wave 1 (48 lanes): poll the 3 remote roles' 16 dwords each
      int k  = tid - 64;                       // 0..47
      int rr = (role + 1 + (k >> 4)) & 3;      // the 3 other roles
      int m  = 16 * rr + (k & 15);
      unsigned v;
      do {
        v = __hip_atomic_load(hxb + parQ * 64 + m, __ATOMIC_RELAXED,
                              __HIP_MEMORY_SCOPE_AGENT);
      } while ((v & 1u) != tauQ);
      hds8[m] = v;                             // lsb-tag noise: 1/127 on 1 of 4
    }
    __syncthreads();
  }
}

// ---------------------------------------------------------------------------
// log_lam_tgt, fully parallel: one wave per (b,t). Recomputes h_next from the
// packed state (same formula as sampling with dt = dtime[t+1]).
__global__ __launch_bounds__(256) void k_post(
    const uint2* __restrict__ state, const int* __restrict__ event,
    const float* __restrict__ dtime, const float* __restrict__ Wl,
    float* __restrict__ loglik_sum) {
  const int wid = blockIdx.x * 4 + (threadIdx.x >> 6);  // 0..65471
  const int lane = threadIdx.x & 63;
  const int b = wid / Tn;
  const int t = wid - b * Tn;
  const int tgt = event[b * TP2n + t + 1];
  if (tgt >= Kn) return;                                 // wave-uniform
  const float dtv = dtime[b * TP2n + t + 1];
  const uint2* srow = state + (size_t)wid * Hn;
  uint4 sA = *reinterpret_cast<const uint4*>(srow + lane * 4);
  uint4 sB = *reinterpret_cast<const uint4*>(srow + lane * 4 + 2);
  float4 wl = *reinterpret_cast<const float4*>(Wl + tgt * Hn + lane * 4);
  float h[4];
#pragma unroll
  for (int qq = 0; qq < 4; ++qq) {
    unsigned lo = (qq == 0) ? sA.x : (qq == 1) ? sA.z : (qq == 2) ? sB.x : sB.z;
    unsigned hi = (qq == 0) ? sA.y : (qq == 1) ? sA.w : (qq == 2) ? sB.y : sB.w;
    f16x2 p0 = u2h(lo), p1 = u2h(hi);
    float c = p0[0], cb = p0[1], gd = p1[0], go = p1[1];
    float cs = cb + (c - cb) * __expf(-gd * dtv);
    h[qq] = go * tanhfast(cs);
  }
  float d = h[0] * wl.x + h[1] * wl.y + h[2] * wl.z + h[3] * wl.w;
#pragma unroll
  for (int off = 32; off; off >>= 1) d += __shfl_down(d, off);
  if (lane == 0) atomicAdd(&loglik_sum[b], __logf(softplusf(d) + EPSF));
}

// ---------------------------------------------------------------------------
// Sampling: 1024 blocks (16/batch, 64 samples each) x 128 threads; thread k
// holds Wl row k in registers. Packed-state gather (one uint4/thread),
// next-sample prefetch.
__global__ __launch_bounds__(128) void k_samp(
    const uint2* __restrict__ state, const float* __restrict__ Wl,
    const int* __restrict__ sidx, const float* __restrict__ sdt,
    const float* __restrict__ smask,
    float* __restrict__ lam_acc, float* __restrict__ mask_acc) {
  const int blk = blockIdx.x;
  const int b = blk >> 4;
  const int base = (b << 10) + (blk & 15) * 64;
  const int tid = threadIdx.x;

  f16x2 wr[128];
  {
    const float* wrow = Wl + tid * Hn;
#pragma unroll
    for (int i = 0; i < 128; ++i) {
      f16x2 v; v[0] = (_Float16)wrow[2 * i]; v[1] = (_Float16)wrow[2 * i + 1];
      wr[i] = v;
    }
  }
  __shared__ float4 hy4[Hn / 8];
  __shared__ float  red[2];
  float accl = 0.f, accm = 0.f;

  int   row = sidx[base];
  float dtv = sdt[base];
  float mk  = smask[base];
  uint4 st = *reinterpret_cast<const uint4*>(state + (size_t)row * Hn + 2 * tid);

  for (int s = 0; s < 64; ++s) {
    f16x2 p0 = u2h(st.x), p1 = u2h(st.y);
    f16x2 q0 = u2h(st.z), q1 = u2h(st.w);
    float cs0 = (float)p0[1] + ((float)p0[0] - (float)p0[1]) * __expf(-(float)p1[0] * dtv);
    float cs1 = (float)q0[1] + ((float)q0[0] - (float)q0[1]) * __expf(-(float)q1[0] * dtv);
    f16x2 hp;
    hp[0] = (_Float16)((float)p1[1] * tanhfast(cs0));
    hp[1] = (_Float16)((float)q1[1] * tanhfast(cs1));
    reinterpret_cast<unsigned*>(hy4)[tid] = __builtin_bit_cast(unsigned, hp);

    uint4 st_n = st; float dt_n = dtv, mk_n = mk;
    if (s < 63) {
      int sg = base + s + 1;
      int r2 = sidx[sg];
      dt_n = sdt[sg];
      mk_n = smask[sg];
      st_n = *reinterpret_cast<const uint4*>(state + (size_t)r2 * Hn + 2 * tid);
    }
    __syncthreads();

    float d = 0.f;
#pragma unroll
    for (int q = 0; q < 32; ++q) {
      float4 hq = hy4[q];
      d = fdot2f(wr[4 * q + 0], f2h(hq.x), d);
      d = fdot2f(wr[4 * q + 1], f2h(hq.y), d);
      d = fdot2f(wr[4 * q + 2], f2h(hq.z), d);
      d = fdot2f(wr[4 * q + 3], f2h(hq.w), d);
    }
    float lam = softplusf(d);
#pragma unroll
    for (int off = 32; off; off >>= 1) lam += __shfl_down(lam, off);
    if ((tid & 63) == 0) red[tid >> 6] = lam;
    __syncthreads();
    if (tid == 0) {
      accl += (red[0] + red[1]) * mk;
      accm += mk;
    }
    st = st_n; dtv = dt_n; mk = mk_n;
  }
  if (tid == 0) {
    atomicAdd(&lam_acc[b], accl);
    atomicAdd(&mask_acc[b], accm);
  }
}

// ---------------------------------------------------------------------------
__global__ void k_final(const float* __restrict__ loglik_sum,
                        const float* __restrict__ lam_acc,
                        const float* __restrict__ mask_acc,
                        const float* __restrict__ duration,
                        float* __restrict__ out) {
  int b = threadIdx.x;
  if (b < Bn) out[b] = loglik_sum[b] - (lam_acc[b] / mask_acc[b]) * duration[b];
}

// ---------------------------------------------------------------------------
extern "C" void kernel_launch(void* const* d_in, const int* in_sizes, int n_in,
                              void* d_out, int out_size, void* d_ws, size_t ws_size,
                              hipStream_t stream) {
  const int*   event    = (const int*)d_in[0];
  const float* dtime    = (const float*)d_in[1];
  const float* duration = (const float*)d_in[3];
  const float* sdt      = (const float*)d_in[4];
  const int*   sidx     = (const int*)d_in[5];
  const float* smask    = (const float*)d_in[6];
  const float* Emb      = (const float*)d_in[7];
  const float* W        = (const float*)d_in[8];
  const float* bv       = (const float*)d_in[9];
  const float* Wl       = (const float*)d_in[10];

  char* ws = (char*)d_ws;
  // layout: EWp(0.94MB)@0 | wq(448KB)@1MB | acc(768B)@2MB | hx(32KB)@2MB+8KB |
  //         sc(7KB)@2MB+48KB | packed state(134MB)@4MB
  float*    EW         = (float*)(ws + 0);
  unsigned* wq         = (unsigned*)(ws + (1u << 20));
  float*    lam_acc    = (float*)(ws + (2u << 20));
  float*    mask_acc   = lam_acc + 64;
  float*    loglik_sum = lam_acc + 128;
  unsigned* hx         = (unsigned*)(ws + (2u << 20) + 8192);
  float*    sc         = (float*)(ws + (2u << 20) + 49152);
  uint2*    state      = (uint2*)(ws + (4u << 20));

  k_ew<<<dim3(NEn), dim3(256), 0, stream>>>(Emb, W, bv, EW);
  k_wq8<<<dim3(H7n), dim3(64), 0, stream>>>(W, wq, sc);
  k_init<<<dim3(1), dim3(1024), 0, stream>>>(lam_acc, hx);
  k_scan<<<dim3(256), dim3(448), 0, stream>>>(event, dtime, EW, wq, sc, hx,
                                              state);
  k_post<<<dim3(16368), dim3(256), 0, stream>>>(state, event, dtime, Wl,
                                                loglik_sum);
  k_samp<<<dim3(1024), dim3(128), 0, stream>>>(state, Wl, sidx, sdt, smask,
                                               lam_acc, mask_acc);
  k_final<<<dim3(1), dim3(64), 0, stream>>>(loglik_sum, lam_acc, mask_acc,
                                            duration, (float*)d_out);
}